// Round 4
// baseline (8314.974 us; speedup 1.0000x reference)
//
#include <hip/hip_runtime.h>
#include <math.h>

#define BB 16
#define LL 128
#define HH 1024
#define EE 512
#define VV 32000
#define G3 3072
#define NBLK 256

__device__ __forceinline__ float sigmoidf_(float x){ return 1.0f/(1.0f+expf(-x)); }

__global__ void k_rowidx(const int* __restrict__ inp, int* __restrict__ idx){
  int r = blockIdx.x*256 + threadIdx.x;
  if (r < 2048){ int l = r >> 4, b = r & 15; idx[r] = inp[b*LL + l]; }
}

template<int ACT, int KK>
__global__ __launch_bounds__(256) void k_gemm(const float* __restrict__ A, const int* __restrict__ rowidx,
                       const float* __restrict__ Bm, const float* __restrict__ bias,
                       float* __restrict__ C, int N){
  constexpr int KS = (KK==512)?9:10;
  __shared__ float As[32*KK];
  const int tid = threadIdx.x;
  const int r0 = blockIdx.x*32;
  const int c  = blockIdx.y*512 + (tid<<1);
  for (int i = tid; i < 32*KK; i += 256){
    int rr = i >> KS;
    int row = r0 + rr;
    int arow = rowidx ? rowidx[row] : row;
    int kk = i - (rr<<KS);
    As[i] = A[(size_t)arow*KK + kk];
  }
  __syncthreads();
  float2 acc[32];
  #pragma unroll
  for (int r=0;r<32;r++){ acc[r].x=0.f; acc[r].y=0.f; }
  for (int k=0;k<KK;k++){
    const float2 w = *(const float2*)(Bm + (size_t)k*N + c);
    #pragma unroll
    for (int r=0;r<32;r++){
      float a = As[(r<<KS)+k];
      acc[r].x = fmaf(a,w.x,acc[r].x);
      acc[r].y = fmaf(a,w.y,acc[r].y);
    }
  }
  const float2 bv = *(const float2*)(bias + c);
  #pragma unroll
  for (int r=0;r<32;r++){
    float x = acc[r].x + bv.x, y = acc[r].y + bv.y;
    if (ACT==1){ x = tanhf(x); y = tanhf(y); }
    *(float2*)(C + (size_t)(r0+r)*N + c) = make_float2(x,y);
  }
}

__global__ void k_gx0(const float* __restrict__ emb, const float* __restrict__ Wih0,
                      const float* __restrict__ bih0, float* __restrict__ gx0){
  int j = blockIdx.x*256 + threadIdx.x;
  float acc = bih0[j];
  const float* e = emb + EE;
  for (int k=0;k<EE;k++) acc = fmaf(e[k], Wih0[(size_t)k*G3 + j], acc);
  gx0[j] = acc;
}

// Persistent GRU chain. Weights LDS-resident; coalesced h loads; intra-wave
// shuffle k-reduction. Grid sync = contention-free flag barrier: 256 flags on
// separate cachelines, symmetric all-poll (thread t polls block t's flag).
__global__ __launch_bounds__(256,1) void k_chain_persist(
    const float* Hinit, float* Hall, const float* __restrict__ W,
    const float* __restrict__ gxbase, int gx_sstride, int gx_bstride,
    const float* __restrict__ bhh, int* flags, int epoch)
{
  __shared__ float wl[12][1024];
  const int tid = threadIdx.x;
  const int kc  = tid & 63;
  const int bc  = tid >> 6;
  const int jb  = blockIdx.x << 2;
  const int b0  = bc << 2;

  for (int i = tid; i < 3072; i += 256){
    int g = i >> 10, k = i & 1023;
    const float4 w4 = *(const float4*)(W + (size_t)k*G3 + g*1024 + jb);
    wl[g*4+0][k] = w4.x; wl[g*4+1][k] = w4.y; wl[g*4+2][k] = w4.z; wl[g*4+3][k] = w4.w;
  }
  __syncthreads();

  const int jl = kc & 3, bi_p = kc >> 2;
  const int jp = jb + jl, bp = b0 + bi_p;
  float br = 0.f, bz = 0.f, bn = 0.f;
  if (kc < 16){ br = bhh[jp]; bz = bhh[1024+jp]; bn = bhh[2048+jp]; }

  for (int s = 0; s < LL; s++){
    const float* hp = (s==0) ? Hinit : (Hall + (size_t)(s-1)*(BB*HH));
    float4 h4[4][4];
    #pragma unroll
    for (int bi=0; bi<4; bi++)
      #pragma unroll
      for (int q=0; q<4; q++)
        h4[bi][q] = *(const float4*)(hp + (size_t)(b0+bi)*HH + q*256 + (kc<<2));

    float acc[12][4];
    #pragma unroll
    for (int c=0;c<12;c++)
      #pragma unroll
      for (int bi=0;bi<4;bi++) acc[c][bi] = 0.f;

    #pragma unroll
    for (int c=0;c<12;c++){
      const float4* wc = (const float4*)(&wl[c][0]);
      float4 wA = wc[kc];
      float4 wB = wc[64 + kc];
      float4 wC = wc[128 + kc];
      float4 wD = wc[192 + kc];
      #pragma unroll
      for (int bi=0; bi<4; bi++){
        float v = acc[c][bi];
        v = fmaf(wA.x, h4[bi][0].x, v); v = fmaf(wA.y, h4[bi][0].y, v);
        v = fmaf(wA.z, h4[bi][0].z, v); v = fmaf(wA.w, h4[bi][0].w, v);
        v = fmaf(wB.x, h4[bi][1].x, v); v = fmaf(wB.y, h4[bi][1].y, v);
        v = fmaf(wB.z, h4[bi][1].z, v); v = fmaf(wB.w, h4[bi][1].w, v);
        v = fmaf(wC.x, h4[bi][2].x, v); v = fmaf(wC.y, h4[bi][2].y, v);
        v = fmaf(wC.z, h4[bi][2].z, v); v = fmaf(wC.w, h4[bi][2].w, v);
        v = fmaf(wD.x, h4[bi][3].x, v); v = fmaf(wD.y, h4[bi][3].y, v);
        v = fmaf(wD.z, h4[bi][3].z, v); v = fmaf(wD.w, h4[bi][3].w, v);
        acc[c][bi] = v;
      }
    }

    #pragma unroll
    for (int c=0;c<12;c++)
      #pragma unroll
      for (int bi=0;bi<4;bi++){
        float v = acc[c][bi];
        v += __shfl_xor(v, 1,  64);
        v += __shfl_xor(v, 2,  64);
        v += __shfl_xor(v, 4,  64);
        v += __shfl_xor(v, 8,  64);
        v += __shfl_xor(v, 16, 64);
        v += __shfl_xor(v, 32, 64);
        acc[c][bi] = v;
      }

    if (kc < 16){
      float ghr = 0.f, ghz = 0.f, ghn = 0.f;
      #pragma unroll
      for (int c=0;c<4;c++)
        #pragma unroll
        for (int bi=0;bi<4;bi++){
          bool sel = (jl==c) & (bi_p==bi);
          ghr = sel ? acc[c][bi]   : ghr;
          ghz = sel ? acc[4+c][bi] : ghz;
          ghn = sel ? acc[8+c][bi] : ghn;
        }
      const float* gx = gxbase + (size_t)s*gx_sstride + (size_t)bp*gx_bstride;
      float r = sigmoidf_(gx[jp]      + ghr + br);
      float z = sigmoidf_(gx[1024+jp] + ghz + bz);
      float n = tanhf    (gx[2048+jp] + r*(ghn + bn));
      float hprev = hp[(size_t)bp*HH + jp];
      Hall[(size_t)s*(BB*HH) + (size_t)bp*HH + jp] = (1.f-z)*n + z*hprev;
    }

    if (s < LL-1){
      const int val = epoch*LL + s + 1;
      __syncthreads();                // block's h-writes done
      if (tid == 0)
        __hip_atomic_store(&flags[(int)blockIdx.x*32], val,
                           __ATOMIC_RELEASE, __HIP_MEMORY_SCOPE_AGENT);
      // symmetric all-poll: thread t waits for block t's flag
      while (__hip_atomic_load(&flags[tid*32], __ATOMIC_RELAXED,
                               __HIP_MEMORY_SCOPE_AGENT) < val){
        __builtin_amdgcn_s_sleep(1);
      }
      __threadfence();                // acquire others' h-writes
      __syncthreads();
    }
  }
}

__global__ __launch_bounds__(256) void k_attn(const float* __restrict__ enc, const float* __restrict__ H1,
                       float* __restrict__ ctx){
  __shared__ float h1s[8][HH];
  __shared__ float sc[8][LL];
  __shared__ float part[2][8][LL];
  const int tid = threadIdx.x;
  const int s0 = blockIdx.x*8, b = blockIdx.y;
  for (int i = tid; i < 8*HH; i += 256){
    int si = i >> 10, k = i & 1023;
    h1s[si][k] = H1[(size_t)(s0+si)*BB*HH + (size_t)b*HH + k];
  }
  __syncthreads();
  {
    const int l = tid & 127, half = tid >> 7;
    const float4* er = (const float4*)(enc + ((size_t)l*BB + b)*HH + half*512);
    float a[8];
    #pragma unroll
    for (int s=0;s<8;s++) a[s]=0.f;
    for (int q=0;q<128;q++){
      float4 e = er[q];
      #pragma unroll
      for (int s=0;s<8;s++){
        const float4 h = *(const float4*)(&h1s[s][half*512 + q*4]);
        a[s] += h.x*e.x + h.y*e.y + h.z*e.z + h.w*e.w;
      }
    }
    #pragma unroll
    for (int s=0;s<8;s++) part[half][s][l] = a[s];
  }
  __syncthreads();
  for (int p = tid; p < 1024; p += 256){
    int s = p >> 7, l = p & 127;
    sc[s][l] = (part[0][s][l] + part[1][s][l]) * 0.03125f;
  }
  __syncthreads();
  {
    int s = tid >> 5, lid = tid & 31;
    float v0 = sc[s][lid], v1 = sc[s][lid+32], v2 = sc[s][lid+64], v3 = sc[s][lid+96];
    float m = fmaxf(fmaxf(v0,v1),fmaxf(v2,v3));
    for (int off=16; off>=1; off>>=1) m = fmaxf(m, __shfl_xor(m, off, 32));
    float e0=__expf(v0-m), e1=__expf(v1-m), e2=__expf(v2-m), e3=__expf(v3-m);
    float ssum = e0+e1+e2+e3;
    for (int off=16; off>=1; off>>=1) ssum += __shfl_xor(ssum, off, 32);
    float inv = 1.0f/ssum;
    sc[s][lid]=e0*inv; sc[s][lid+32]=e1*inv; sc[s][lid+64]=e2*inv; sc[s][lid+96]=e3*inv;
  }
  __syncthreads();
  {
    float acc[4][8];
    #pragma unroll
    for (int q=0;q<4;q++)
      #pragma unroll
      for (int s=0;s<8;s++) acc[q][s]=0.f;
    for (int l=0;l<128;l++){
      const float* er = enc + ((size_t)l*BB + b)*HH + tid;
      float a[8];
      #pragma unroll
      for (int s=0;s<8;s++) a[s] = sc[s][l];
      #pragma unroll
      for (int q=0;q<4;q++){
        float e = er[q*256];
        #pragma unroll
        for (int s=0;s<8;s++) acc[q][s] = fmaf(a[s], e, acc[q][s]);
      }
    }
    #pragma unroll
    for (int s=0;s<8;s++)
      #pragma unroll
      for (int q=0;q<4;q++)
        ctx[(size_t)(s0+s)*BB*HH + (size_t)b*HH + tid + q*256] = acc[q][s];
  }
}

__global__ __launch_bounds__(256) void k_logit(const float* __restrict__ H1, const float* __restrict__ ctx,
                        const float* __restrict__ Wout, const float* __restrict__ bout,
                        const int* __restrict__ inp, const int* __restrict__ ts,
                        float* __restrict__ outp, float* __restrict__ bce){
  __shared__ float rbuf[256];
  const int i = blockIdx.x;
  const int b = i >> 7, t = i & 127;
  const int v = inp[b*LL + t];
  const int tid = threadIdx.x;
  const float* h1r = H1 + ((size_t)t*BB + b)*HH;
  const float* cxr = ctx + ((size_t)t*BB + b)*HH;
  float acc = 0.f;
  #pragma unroll
  for (int q=0;q<4;q++){
    int k = tid + q*256;
    acc = fmaf(h1r[k], Wout[(size_t)k*VV + v], acc);
  }
  #pragma unroll
  for (int q=0;q<4;q++){
    int k = tid + q*256;
    acc = fmaf(cxr[k], Wout[(size_t)(k+1024)*VV + v], acc);
  }
  rbuf[tid] = acc;
  __syncthreads();
  for (int s=128; s>0; s>>=1){
    if (tid < s) rbuf[tid] += rbuf[tid+s];
    __syncthreads();
  }
  if (tid==0){
    float logit = rbuf[0] + bout[v];
    float p = 1.0f/(1.0f + expf(-logit));
    outp[b*LL + t] = p;
    float pc = fminf(fmaxf(p, 1e-12f), 1.0f - 1e-7f);
    float tg = (float)ts[0];
    bce[i] = -(tg*logf(pc) + (1.0f-tg)*log1pf(-pc));
  }
}

__global__ void k_loss(const float* __restrict__ bce, float* __restrict__ out0){
  __shared__ float rbuf[256];
  int tid = threadIdx.x;
  float s = 0.f;
  for (int i = tid; i < 2048; i += 256) s += bce[i];
  rbuf[tid] = s; __syncthreads();
  for (int st=128; st>0; st>>=1){
    if (tid<st) rbuf[tid]+=rbuf[tid+st];
    __syncthreads();
  }
  if (tid==0) out0[0] = rbuf[0] * (1.0f/(2048.0f*16.0f));
}

extern "C" void kernel_launch(void* const* d_in, const int* in_sizes, int n_in,
                              void* d_out, int out_size, void* d_ws, size_t ws_size,
                              hipStream_t stream){
  (void)in_sizes; (void)n_in; (void)out_size; (void)ws_size;
  const int*   inp   = (const int*)d_in[0];
  const int*   ts    = (const int*)d_in[2];
  const float* emb   = (const float*)d_in[3];
  const float* encW  = (const float*)d_in[4];
  const float* encb  = (const float*)d_in[5];
  const float* Wih0  = (const float*)d_in[6];
  const float* Whh0  = (const float*)d_in[7];
  const float* bih0  = (const float*)d_in[8];
  const float* bhh0  = (const float*)d_in[9];
  const float* Wih1  = (const float*)d_in[10];
  const float* Whh1  = (const float*)d_in[11];
  const float* bih1  = (const float*)d_in[12];
  const float* bhh1  = (const float*)d_in[13];
  const float* Wout  = (const float*)d_in[14];
  const float* bout  = (const float*)d_in[15];
  float* out = (float*)d_out;

  float* ws      = (float*)d_ws;
  float* enc_out = ws;
  float* H0      = enc_out + 2097152;
  float* H1      = H0 + 2097152;
  float* GX1     = H1 + 2097152;
  float* CTX     = GX1 + 6291456;
  float* gx0     = CTX + 2097152;
  float* bceb    = gx0 + 3072;
  int*   rowidx  = (int*)(bceb + 2048);
  int*   flags   = rowidx + 2048;          // 256 flags x 32 ints (128B lines)

  hipMemsetAsync(flags, 0, 256*32*sizeof(int), stream);
  k_rowidx<<<8,256,0,stream>>>(inp, rowidx);
  k_gemm<1,512><<<dim3(64,2),256,0,stream>>>(emb, rowidx, encW, encb, enc_out, HH);
  k_gx0<<<12,256,0,stream>>>(emb, Wih0, bih0, gx0);

  const float* enclast = enc_out + (size_t)127*BB*HH;

  k_chain_persist<<<NBLK,256,0,stream>>>(enclast, H0, Whh0, gx0, 0, 0, bhh0, flags, 0);
  k_gemm<0,1024><<<dim3(64,6),256,0,stream>>>(H0, nullptr, Wih1, bih1, GX1, G3);
  k_chain_persist<<<NBLK,256,0,stream>>>(enclast, H1, Whh1, GX1, BB*G3, G3, bhh1, flags, 1);
  k_attn<<<dim3(16,16),256,0,stream>>>(enc_out, H1, CTX);
  k_logit<<<2048,256,0,stream>>>(H1, CTX, Wout, bout, inp, ts, out+1, bceb);
  k_loss<<<1,256,0,stream>>>(bceb, out);
}

// Round 5
// 3663.643 us; speedup vs baseline: 2.2696x; 2.2696x over previous
//
#include <hip/hip_runtime.h>
#include <math.h>

#define BB 16
#define LL 128
#define HH 1024
#define EE 512
#define VV 32000
#define G3 3072
#define NBLK 256

__device__ __forceinline__ float sigmoidf_(float x){ return 1.0f/(1.0f+expf(-x)); }

__global__ void k_rowidx(const int* __restrict__ inp, int* __restrict__ idx){
  int r = blockIdx.x*256 + threadIdx.x;
  if (r < 2048){ int l = r >> 4, b = r & 15; idx[r] = inp[b*LL + l]; }
}

template<int ACT, int KK>
__global__ __launch_bounds__(256) void k_gemm(const float* __restrict__ A, const int* __restrict__ rowidx,
                       const float* __restrict__ Bm, const float* __restrict__ bias,
                       float* __restrict__ C, int N){
  constexpr int KS = (KK==512)?9:10;
  __shared__ float As[32*KK];
  const int tid = threadIdx.x;
  const int r0 = blockIdx.x*32;
  const int c  = blockIdx.y*512 + (tid<<1);
  for (int i = tid; i < 32*KK; i += 256){
    int rr = i >> KS;
    int row = r0 + rr;
    int arow = rowidx ? rowidx[row] : row;
    int kk = i - (rr<<KS);
    As[i] = A[(size_t)arow*KK + kk];
  }
  __syncthreads();
  float2 acc[32];
  #pragma unroll
  for (int r=0;r<32;r++){ acc[r].x=0.f; acc[r].y=0.f; }
  for (int k=0;k<KK;k++){
    const float2 w = *(const float2*)(Bm + (size_t)k*N + c);
    #pragma unroll
    for (int r=0;r<32;r++){
      float a = As[(r<<KS)+k];
      acc[r].x = fmaf(a,w.x,acc[r].x);
      acc[r].y = fmaf(a,w.y,acc[r].y);
    }
  }
  const float2 bv = *(const float2*)(bias + c);
  #pragma unroll
  for (int r=0;r<32;r++){
    float x = acc[r].x + bv.x, y = acc[r].y + bv.y;
    if (ACT==1){ x = tanhf(x); y = tanhf(y); }
    *(float2*)(C + (size_t)(r0+r)*N + c) = make_float2(x,y);
  }
}

__global__ void k_gx0(const float* __restrict__ emb, const float* __restrict__ Wih0,
                      const float* __restrict__ bih0, float* __restrict__ gx0){
  int j = blockIdx.x*256 + threadIdx.x;
  float acc = bih0[j];
  const float* e = emb + EE;
  for (int k=0;k<EE;k++) acc = fmaf(e[k], Wih0[(size_t)k*G3 + j], acc);
  gx0[j] = acc;
}

// Persistent GRU chain, fence-free cross-XCD handshake:
//  - h published via relaxed agent-scope atomic stores (write-through, no wbl2)
//  - per-wave s_waitcnt vmcnt(0) + block barrier, then one relaxed flag store
//  - readers poll flags with agent-scope loads (L2-bypassing); h itself is
//    read with plain vectorized loads: each step reads a fresh address range,
//    so local caches cannot hold stale copies. NO __threadfence anywhere.
__global__ __launch_bounds__(256,1) void k_chain_persist(
    const float* Hinit, float* Hall, const float* __restrict__ W,
    const float* __restrict__ gxbase, int gx_sstride, int gx_bstride,
    const float* __restrict__ bhh, int* flags, int epoch)
{
  __shared__ float wl[12][1024];
  const int tid = threadIdx.x;
  const int kc  = tid & 63;
  const int bc  = tid >> 6;
  const int jb  = blockIdx.x << 2;
  const int b0  = bc << 2;

  for (int i = tid; i < 3072; i += 256){
    int g = i >> 10, k = i & 1023;
    const float4 w4 = *(const float4*)(W + (size_t)k*G3 + g*1024 + jb);
    wl[g*4+0][k] = w4.x; wl[g*4+1][k] = w4.y; wl[g*4+2][k] = w4.z; wl[g*4+3][k] = w4.w;
  }
  __syncthreads();

  const int jl = kc & 3, bi_p = kc >> 2;
  const int jp = jb + jl, bp = b0 + bi_p;
  float br = 0.f, bz = 0.f, bn = 0.f;
  if (kc < 16){ br = bhh[jp]; bz = bhh[1024+jp]; bn = bhh[2048+jp]; }

  for (int s = 0; s < LL; s++){
    const float* hp = (s==0) ? Hinit : (Hall + (size_t)(s-1)*(BB*HH));
    float4 h4[4][4];
    #pragma unroll
    for (int bi=0; bi<4; bi++)
      #pragma unroll
      for (int q=0; q<4; q++)
        h4[bi][q] = *(const float4*)(hp + (size_t)(b0+bi)*HH + q*256 + (kc<<2));

    float acc[12][4];
    #pragma unroll
    for (int c=0;c<12;c++)
      #pragma unroll
      for (int bi=0;bi<4;bi++) acc[c][bi] = 0.f;

    #pragma unroll
    for (int c=0;c<12;c++){
      const float4* wc = (const float4*)(&wl[c][0]);
      float4 wA = wc[kc];
      float4 wB = wc[64 + kc];
      float4 wC = wc[128 + kc];
      float4 wD = wc[192 + kc];
      #pragma unroll
      for (int bi=0; bi<4; bi++){
        float v = acc[c][bi];
        v = fmaf(wA.x, h4[bi][0].x, v); v = fmaf(wA.y, h4[bi][0].y, v);
        v = fmaf(wA.z, h4[bi][0].z, v); v = fmaf(wA.w, h4[bi][0].w, v);
        v = fmaf(wB.x, h4[bi][1].x, v); v = fmaf(wB.y, h4[bi][1].y, v);
        v = fmaf(wB.z, h4[bi][1].z, v); v = fmaf(wB.w, h4[bi][1].w, v);
        v = fmaf(wC.x, h4[bi][2].x, v); v = fmaf(wC.y, h4[bi][2].y, v);
        v = fmaf(wC.z, h4[bi][2].z, v); v = fmaf(wC.w, h4[bi][2].w, v);
        v = fmaf(wD.x, h4[bi][3].x, v); v = fmaf(wD.y, h4[bi][3].y, v);
        v = fmaf(wD.z, h4[bi][3].z, v); v = fmaf(wD.w, h4[bi][3].w, v);
        acc[c][bi] = v;
      }
    }

    #pragma unroll
    for (int c=0;c<12;c++)
      #pragma unroll
      for (int bi=0;bi<4;bi++){
        float v = acc[c][bi];
        v += __shfl_xor(v, 1,  64);
        v += __shfl_xor(v, 2,  64);
        v += __shfl_xor(v, 4,  64);
        v += __shfl_xor(v, 8,  64);
        v += __shfl_xor(v, 16, 64);
        v += __shfl_xor(v, 32, 64);
        acc[c][bi] = v;
      }

    if (kc < 16){
      float ghr = 0.f, ghz = 0.f, ghn = 0.f;
      #pragma unroll
      for (int c=0;c<4;c++)
        #pragma unroll
        for (int bi=0;bi<4;bi++){
          bool sel = (jl==c) & (bi_p==bi);
          ghr = sel ? acc[c][bi]   : ghr;
          ghz = sel ? acc[4+c][bi] : ghz;
          ghn = sel ? acc[8+c][bi] : ghn;
        }
      const float* gx = gxbase + (size_t)s*gx_sstride + (size_t)bp*gx_bstride;
      float r = sigmoidf_(gx[jp]      + ghr + br);
      float z = sigmoidf_(gx[1024+jp] + ghz + bz);
      float n = tanhf    (gx[2048+jp] + r*(ghn + bn));
      float hprev = hp[(size_t)bp*HH + jp];
      float hnew  = (1.f-z)*n + z*hprev;
      // publish: agent-scope write-through store (no L2 flush needed)
      __hip_atomic_store((int*)&Hall[(size_t)s*(BB*HH) + (size_t)bp*HH + jp],
                         __float_as_int(hnew),
                         __ATOMIC_RELAXED, __HIP_MEMORY_SCOPE_AGENT);
    }

    if (s < LL-1){
      const int val = epoch*LL + s + 1;
      // wait for this wave's h-stores to reach the coherence point
      asm volatile("s_waitcnt vmcnt(0)" ::: "memory");
      __syncthreads();              // all waves' stores ack'd
      if (tid == 0)
        __hip_atomic_store(&flags[(int)blockIdx.x*32], val,
                           __ATOMIC_RELAXED, __HIP_MEMORY_SCOPE_AGENT);
      // symmetric all-poll: thread t waits for block t's flag (L2-bypassing)
      while (__hip_atomic_load(&flags[tid*32], __ATOMIC_RELAXED,
                               __HIP_MEMORY_SCOPE_AGENT) < val){
        __builtin_amdgcn_s_sleep(4);
      }
      __syncthreads();              // exec + compiler memory barrier
    }
  }
}

__global__ __launch_bounds__(256) void k_attn(const float* __restrict__ enc, const float* __restrict__ H1,
                       float* __restrict__ ctx){
  __shared__ float h1s[8][HH];
  __shared__ float sc[8][LL];
  __shared__ float part[2][8][LL];
  const int tid = threadIdx.x;
  const int s0 = blockIdx.x*8, b = blockIdx.y;
  for (int i = tid; i < 8*HH; i += 256){
    int si = i >> 10, k = i & 1023;
    h1s[si][k] = H1[(size_t)(s0+si)*BB*HH + (size_t)b*HH + k];
  }
  __syncthreads();
  {
    const int l = tid & 127, half = tid >> 7;
    const float4* er = (const float4*)(enc + ((size_t)l*BB + b)*HH + half*512);
    float a[8];
    #pragma unroll
    for (int s=0;s<8;s++) a[s]=0.f;
    for (int q=0;q<128;q++){
      float4 e = er[q];
      #pragma unroll
      for (int s=0;s<8;s++){
        const float4 h = *(const float4*)(&h1s[s][half*512 + q*4]);
        a[s] += h.x*e.x + h.y*e.y + h.z*e.z + h.w*e.w;
      }
    }
    #pragma unroll
    for (int s=0;s<8;s++) part[half][s][l] = a[s];
  }
  __syncthreads();
  for (int p = tid; p < 1024; p += 256){
    int s = p >> 7, l = p & 127;
    sc[s][l] = (part[0][s][l] + part[1][s][l]) * 0.03125f;
  }
  __syncthreads();
  {
    int s = tid >> 5, lid = tid & 31;
    float v0 = sc[s][lid], v1 = sc[s][lid+32], v2 = sc[s][lid+64], v3 = sc[s][lid+96];
    float m = fmaxf(fmaxf(v0,v1),fmaxf(v2,v3));
    for (int off=16; off>=1; off>>=1) m = fmaxf(m, __shfl_xor(m, off, 32));
    float e0=__expf(v0-m), e1=__expf(v1-m), e2=__expf(v2-m), e3=__expf(v3-m);
    float ssum = e0+e1+e2+e3;
    for (int off=16; off>=1; off>>=1) ssum += __shfl_xor(ssum, off, 32);
    float inv = 1.0f/ssum;
    sc[s][lid]=e0*inv; sc[s][lid+32]=e1*inv; sc[s][lid+64]=e2*inv; sc[s][lid+96]=e3*inv;
  }
  __syncthreads();
  {
    float acc[4][8];
    #pragma unroll
    for (int q=0;q<4;q++)
      #pragma unroll
      for (int s=0;s<8;s++) acc[q][s]=0.f;
    for (int l=0;l<128;l++){
      const float* er = enc + ((size_t)l*BB + b)*HH + tid;
      float a[8];
      #pragma unroll
      for (int s=0;s<8;s++) a[s] = sc[s][l];
      #pragma unroll
      for (int q=0;q<4;q++){
        float e = er[q*256];
        #pragma unroll
        for (int s=0;s<8;s++) acc[q][s] = fmaf(a[s], e, acc[q][s]);
      }
    }
    #pragma unroll
    for (int s=0;s<8;s++)
      #pragma unroll
      for (int q=0;q<4;q++)
        ctx[(size_t)(s0+s)*BB*HH + (size_t)b*HH + tid + q*256] = acc[q][s];
  }
}

__global__ __launch_bounds__(256) void k_logit(const float* __restrict__ H1, const float* __restrict__ ctx,
                        const float* __restrict__ Wout, const float* __restrict__ bout,
                        const int* __restrict__ inp, const int* __restrict__ ts,
                        float* __restrict__ outp, float* __restrict__ bce){
  __shared__ float rbuf[256];
  const int i = blockIdx.x;
  const int b = i >> 7, t = i & 127;
  const int v = inp[b*LL + t];
  const int tid = threadIdx.x;
  const float* h1r = H1 + ((size_t)t*BB + b)*HH;
  const float* cxr = ctx + ((size_t)t*BB + b)*HH;
  float acc = 0.f;
  #pragma unroll
  for (int q=0;q<4;q++){
    int k = tid + q*256;
    acc = fmaf(h1r[k], Wout[(size_t)k*VV + v], acc);
  }
  #pragma unroll
  for (int q=0;q<4;q++){
    int k = tid + q*256;
    acc = fmaf(cxr[k], Wout[(size_t)(k+1024)*VV + v], acc);
  }
  rbuf[tid] = acc;
  __syncthreads();
  for (int s=128; s>0; s>>=1){
    if (tid < s) rbuf[tid] += rbuf[tid+s];
    __syncthreads();
  }
  if (tid==0){
    float logit = rbuf[0] + bout[v];
    float p = 1.0f/(1.0f + expf(-logit));
    outp[b*LL + t] = p;
    float pc = fminf(fmaxf(p, 1e-12f), 1.0f - 1e-7f);
    float tg = (float)ts[0];
    bce[i] = -(tg*logf(pc) + (1.0f-tg)*log1pf(-pc));
  }
}

__global__ void k_loss(const float* __restrict__ bce, float* __restrict__ out0){
  __shared__ float rbuf[256];
  int tid = threadIdx.x;
  float s = 0.f;
  for (int i = tid; i < 2048; i += 256) s += bce[i];
  rbuf[tid] = s; __syncthreads();
  for (int st=128; st>0; st>>=1){
    if (tid<st) rbuf[tid]+=rbuf[tid+st];
    __syncthreads();
  }
  if (tid==0) out0[0] = rbuf[0] * (1.0f/(2048.0f*16.0f));
}

extern "C" void kernel_launch(void* const* d_in, const int* in_sizes, int n_in,
                              void* d_out, int out_size, void* d_ws, size_t ws_size,
                              hipStream_t stream){
  (void)in_sizes; (void)n_in; (void)out_size; (void)ws_size;
  const int*   inp   = (const int*)d_in[0];
  const int*   ts    = (const int*)d_in[2];
  const float* emb   = (const float*)d_in[3];
  const float* encW  = (const float*)d_in[4];
  const float* encb  = (const float*)d_in[5];
  const float* Wih0  = (const float*)d_in[6];
  const float* Whh0  = (const float*)d_in[7];
  const float* bih0  = (const float*)d_in[8];
  const float* bhh0  = (const float*)d_in[9];
  const float* Wih1  = (const float*)d_in[10];
  const float* Whh1  = (const float*)d_in[11];
  const float* bih1  = (const float*)d_in[12];
  const float* bhh1  = (const float*)d_in[13];
  const float* Wout  = (const float*)d_in[14];
  const float* bout  = (const float*)d_in[15];
  float* out = (float*)d_out;

  float* ws      = (float*)d_ws;
  float* enc_out = ws;
  float* H0      = enc_out + 2097152;
  float* H1      = H0 + 2097152;
  float* GX1     = H1 + 2097152;
  float* CTX     = GX1 + 6291456;
  float* gx0     = CTX + 2097152;
  float* bceb    = gx0 + 3072;
  int*   rowidx  = (int*)(bceb + 2048);
  int*   flags   = rowidx + 2048;          // 256 flags x 32 ints (128B lines)

  hipMemsetAsync(flags, 0, 256*32*sizeof(int), stream);
  k_rowidx<<<8,256,0,stream>>>(inp, rowidx);
  k_gemm<1,512><<<dim3(64,2),256,0,stream>>>(emb, rowidx, encW, encb, enc_out, HH);
  k_gx0<<<12,256,0,stream>>>(emb, Wih0, bih0, gx0);

  const float* enclast = enc_out + (size_t)127*BB*HH;

  k_chain_persist<<<NBLK,256,0,stream>>>(enclast, H0, Whh0, gx0, 0, 0, bhh0, flags, 0);
  k_gemm<0,1024><<<dim3(64,6),256,0,stream>>>(H0, nullptr, Wih1, bih1, GX1, G3);
  k_chain_persist<<<NBLK,256,0,stream>>>(enclast, H1, Whh1, GX1, BB*G3, G3, bhh1, flags, 1);
  k_attn<<<dim3(16,16),256,0,stream>>>(enc_out, H1, CTX);
  k_logit<<<2048,256,0,stream>>>(H1, CTX, Wout, bout, inp, ts, out+1, bceb);
  k_loss<<<1,256,0,stream>>>(bceb, out);
}

// Round 6
// 2680.235 us; speedup vs baseline: 3.1023x; 1.3669x over previous
//
#include <hip/hip_runtime.h>
#include <math.h>

#define BB 16
#define LL 128
#define HH 1024
#define EE 512
#define VV 32000
#define G3 3072
#define NBLK 256

__device__ __forceinline__ float sigmoidf_(float x){ return 1.0f/(1.0f+expf(-x)); }

__global__ void k_rowidx(const int* __restrict__ inp, int* __restrict__ idx){
  int r = blockIdx.x*256 + threadIdx.x;
  if (r < 2048){ int l = r >> 4, b = r & 15; idx[r] = inp[b*LL + l]; }
}

template<int ACT, int KK>
__global__ __launch_bounds__(256) void k_gemm(const float* __restrict__ A, const int* __restrict__ rowidx,
                       const float* __restrict__ Bm, const float* __restrict__ bias,
                       float* __restrict__ C, int N){
  constexpr int KS = (KK==512)?9:10;
  __shared__ float As[32*KK];
  const int tid = threadIdx.x;
  const int r0 = blockIdx.x*32;
  const int c  = blockIdx.y*512 + (tid<<1);
  for (int i = tid; i < 32*KK; i += 256){
    int rr = i >> KS;
    int row = r0 + rr;
    int arow = rowidx ? rowidx[row] : row;
    int kk = i - (rr<<KS);
    As[i] = A[(size_t)arow*KK + kk];
  }
  __syncthreads();
  float2 acc[32];
  #pragma unroll
  for (int r=0;r<32;r++){ acc[r].x=0.f; acc[r].y=0.f; }
  for (int k=0;k<KK;k++){
    const float2 w = *(const float2*)(Bm + (size_t)k*N + c);
    #pragma unroll
    for (int r=0;r<32;r++){
      float a = As[(r<<KS)+k];
      acc[r].x = fmaf(a,w.x,acc[r].x);
      acc[r].y = fmaf(a,w.y,acc[r].y);
    }
  }
  const float2 bv = *(const float2*)(bias + c);
  #pragma unroll
  for (int r=0;r<32;r++){
    float x = acc[r].x + bv.x, y = acc[r].y + bv.y;
    if (ACT==1){ x = tanhf(x); y = tanhf(y); }
    *(float2*)(C + (size_t)(r0+r)*N + c) = make_float2(x,y);
  }
}

// Tiled GEMM for GX1 = H0(2048x1024) @ Wih1(1024x3072) + bih1.
// BM=128, BN=192, BK=32; grid (16,16) = 256 blocks (one/CU); 42 KB LDS.
// 256 threads: ty=tid>>4 (8-row group), tx=tid&15 (12-col group); acc 8x12.
__global__ __launch_bounds__(256) void k_gemm2(const float* __restrict__ A,
                        const float* __restrict__ Bm, const float* __restrict__ bias,
                        float* __restrict__ C){
  __shared__ float As[32][132];   // [k][m], padded
  __shared__ float Bs[32][196];   // [k][c], padded
  const int tid = threadIdx.x;
  const int r0 = blockIdx.x*128;
  const int c0 = blockIdx.y*192;
  const int tx = tid & 15, ty = tid >> 4;

  float acc[8][12];
  #pragma unroll
  for (int i=0;i<8;i++)
    #pragma unroll
    for (int j=0;j<12;j++) acc[i][j]=0.f;

  const int sm  = tid >> 1;            // 0..127
  const int skh = (tid & 1) * 16;      // 0 or 16
  const int sbk = tid >> 3;            // 0..31
  const int sbc = (tid & 7) * 24;      // 0..168

  for (int k0=0; k0<1024; k0+=32){
    // stage A (transpose to [k][m])
    {
      const float* ar = A + (size_t)(r0+sm)*1024 + k0 + skh;
      float4 a0 = *(const float4*)(ar+0), a1 = *(const float4*)(ar+4);
      float4 a2 = *(const float4*)(ar+8), a3 = *(const float4*)(ar+12);
      As[skh+ 0][sm]=a0.x; As[skh+ 1][sm]=a0.y; As[skh+ 2][sm]=a0.z; As[skh+ 3][sm]=a0.w;
      As[skh+ 4][sm]=a1.x; As[skh+ 5][sm]=a1.y; As[skh+ 6][sm]=a1.z; As[skh+ 7][sm]=a1.w;
      As[skh+ 8][sm]=a2.x; As[skh+ 9][sm]=a2.y; As[skh+10][sm]=a2.z; As[skh+11][sm]=a2.w;
      As[skh+12][sm]=a3.x; As[skh+13][sm]=a3.y; As[skh+14][sm]=a3.z; As[skh+15][sm]=a3.w;
    }
    // stage B (row-major slice)
    {
      const float* br = Bm + (size_t)(k0+sbk)*G3 + c0 + sbc;
      #pragma unroll
      for (int u=0;u<6;u++)
        *(float4*)(&Bs[sbk][sbc + u*4]) = *(const float4*)(br + u*4);
    }
    __syncthreads();
    #pragma unroll
    for (int k=0;k<32;k++){
      float a[8], b[12];
      *(float4*)(&a[0]) = *(const float4*)(&As[k][ty*8]);
      *(float4*)(&a[4]) = *(const float4*)(&As[k][ty*8+4]);
      *(float4*)(&b[0]) = *(const float4*)(&Bs[k][tx*12]);
      *(float4*)(&b[4]) = *(const float4*)(&Bs[k][tx*12+4]);
      *(float4*)(&b[8]) = *(const float4*)(&Bs[k][tx*12+8]);
      #pragma unroll
      for (int i=0;i<8;i++)
        #pragma unroll
        for (int j=0;j<12;j++)
          acc[i][j] = fmaf(a[i], b[j], acc[i][j]);
    }
    __syncthreads();
  }
  #pragma unroll
  for (int i=0;i<8;i++){
    int row = r0 + ty*8 + i;
    float* cr = C + (size_t)row*G3 + c0 + tx*12;
    const float* br = bias + c0 + tx*12;
    #pragma unroll
    for (int j=0;j<12;j++) acc[i][j] += br[j];
    *(float4*)(cr+0) = *(const float4*)(&acc[i][0]);
    *(float4*)(cr+4) = *(const float4*)(&acc[i][4]);
    *(float4*)(cr+8) = *(const float4*)(&acc[i][8]);
  }
}

__global__ void k_gx0(const float* __restrict__ emb, const float* __restrict__ Wih0,
                      const float* __restrict__ bih0, float* __restrict__ gx0){
  int j = blockIdx.x*256 + threadIdx.x;
  float acc = bih0[j];
  const float* e = emb + EE;
  for (int k=0;k<EE;k++) acc = fmaf(e[k], Wih0[(size_t)k*G3 + j], acc);
  gx0[j] = acc;
}

// Persistent GRU chain, fence-free handshake + AGGREGATOR barrier:
//  - h published via relaxed agent-scope stores (write-through), vmcnt(0) drain
//  - each block stores its flag (own cacheline)
//  - block 0 aggregates: 256 threads poll one flag each, then publish one go word
//  - other blocks: single thread polls go; syncthreads releases the block
__global__ __launch_bounds__(256,1) void k_chain_persist(
    const float* Hinit, float* Hall, const float* __restrict__ W,
    const float* __restrict__ gxbase, int gx_sstride, int gx_bstride,
    const float* __restrict__ bhh, int* flags, int* go, int epoch)
{
  __shared__ float wl[12][1024];
  const int tid = threadIdx.x;
  const int kc  = tid & 63;
  const int bc  = tid >> 6;
  const int jb  = blockIdx.x << 2;
  const int b0  = bc << 2;

  for (int i = tid; i < 3072; i += 256){
    int g = i >> 10, k = i & 1023;
    const float4 w4 = *(const float4*)(W + (size_t)k*G3 + g*1024 + jb);
    wl[g*4+0][k] = w4.x; wl[g*4+1][k] = w4.y; wl[g*4+2][k] = w4.z; wl[g*4+3][k] = w4.w;
  }
  __syncthreads();

  const int jl = kc & 3, bi_p = kc >> 2;
  const int jp = jb + jl, bp = b0 + bi_p;
  float br = 0.f, bz = 0.f, bn = 0.f;
  if (kc < 16){ br = bhh[jp]; bz = bhh[1024+jp]; bn = bhh[2048+jp]; }

  for (int s = 0; s < LL; s++){
    const float* hp = (s==0) ? Hinit : (Hall + (size_t)(s-1)*(BB*HH));
    float4 h4[4][4];
    #pragma unroll
    for (int bi=0; bi<4; bi++)
      #pragma unroll
      for (int q=0; q<4; q++)
        h4[bi][q] = *(const float4*)(hp + (size_t)(b0+bi)*HH + q*256 + (kc<<2));

    float acc[12][4];
    #pragma unroll
    for (int c=0;c<12;c++)
      #pragma unroll
      for (int bi=0;bi<4;bi++) acc[c][bi] = 0.f;

    #pragma unroll
    for (int c=0;c<12;c++){
      const float4* wc = (const float4*)(&wl[c][0]);
      float4 wA = wc[kc];
      float4 wB = wc[64 + kc];
      float4 wC = wc[128 + kc];
      float4 wD = wc[192 + kc];
      #pragma unroll
      for (int bi=0; bi<4; bi++){
        float v = acc[c][bi];
        v = fmaf(wA.x, h4[bi][0].x, v); v = fmaf(wA.y, h4[bi][0].y, v);
        v = fmaf(wA.z, h4[bi][0].z, v); v = fmaf(wA.w, h4[bi][0].w, v);
        v = fmaf(wB.x, h4[bi][1].x, v); v = fmaf(wB.y, h4[bi][1].y, v);
        v = fmaf(wB.z, h4[bi][1].z, v); v = fmaf(wB.w, h4[bi][1].w, v);
        v = fmaf(wC.x, h4[bi][2].x, v); v = fmaf(wC.y, h4[bi][2].y, v);
        v = fmaf(wC.z, h4[bi][2].z, v); v = fmaf(wC.w, h4[bi][2].w, v);
        v = fmaf(wD.x, h4[bi][3].x, v); v = fmaf(wD.y, h4[bi][3].y, v);
        v = fmaf(wD.z, h4[bi][3].z, v); v = fmaf(wD.w, h4[bi][3].w, v);
        acc[c][bi] = v;
      }
    }

    #pragma unroll
    for (int c=0;c<12;c++)
      #pragma unroll
      for (int bi=0;bi<4;bi++){
        float v = acc[c][bi];
        v += __shfl_xor(v, 1,  64);
        v += __shfl_xor(v, 2,  64);
        v += __shfl_xor(v, 4,  64);
        v += __shfl_xor(v, 8,  64);
        v += __shfl_xor(v, 16, 64);
        v += __shfl_xor(v, 32, 64);
        acc[c][bi] = v;
      }

    if (kc < 16){
      float ghr = 0.f, ghz = 0.f, ghn = 0.f;
      #pragma unroll
      for (int c=0;c<4;c++)
        #pragma unroll
        for (int bi=0;bi<4;bi++){
          bool sel = (jl==c) & (bi_p==bi);
          ghr = sel ? acc[c][bi]   : ghr;
          ghz = sel ? acc[4+c][bi] : ghz;
          ghn = sel ? acc[8+c][bi] : ghn;
        }
      const float* gx = gxbase + (size_t)s*gx_sstride + (size_t)bp*gx_bstride;
      float r = sigmoidf_(gx[jp]      + ghr + br);
      float z = sigmoidf_(gx[1024+jp] + ghz + bz);
      float n = tanhf    (gx[2048+jp] + r*(ghn + bn));
      float hprev = hp[(size_t)bp*HH + jp];
      float hnew  = (1.f-z)*n + z*hprev;
      __hip_atomic_store((int*)&Hall[(size_t)s*(BB*HH) + (size_t)bp*HH + jp],
                         __float_as_int(hnew),
                         __ATOMIC_RELAXED, __HIP_MEMORY_SCOPE_AGENT);
    }

    if (s < LL-1){
      const int val = epoch*LL + s + 1;
      asm volatile("s_waitcnt vmcnt(0)" ::: "memory");   // h stores at coherence point
      __syncthreads();
      if (tid == 0)
        __hip_atomic_store(&flags[(int)blockIdx.x*32], val,
                           __ATOMIC_RELAXED, __HIP_MEMORY_SCOPE_AGENT);
      if (blockIdx.x == 0){
        // aggregator: thread t waits for block t's flag, then publish go
        while (__hip_atomic_load(&flags[tid*32], __ATOMIC_RELAXED,
                                 __HIP_MEMORY_SCOPE_AGENT) < val){
          __builtin_amdgcn_s_sleep(1);
        }
        __syncthreads();
        if (tid == 0)
          __hip_atomic_store(go, val, __ATOMIC_RELAXED, __HIP_MEMORY_SCOPE_AGENT);
      } else {
        if (tid == 0){
          while (__hip_atomic_load(go, __ATOMIC_RELAXED,
                                   __HIP_MEMORY_SCOPE_AGENT) < val){
            __builtin_amdgcn_s_sleep(1);
          }
        }
        __syncthreads();
      }
    }
  }
}

__global__ __launch_bounds__(256) void k_attn(const float* __restrict__ enc, const float* __restrict__ H1,
                       float* __restrict__ ctx){
  __shared__ float h1s[8][HH];
  __shared__ float sc[8][LL];
  __shared__ float part[2][8][LL];
  const int tid = threadIdx.x;
  const int s0 = blockIdx.x*8, b = blockIdx.y;
  for (int i = tid; i < 8*HH; i += 256){
    int si = i >> 10, k = i & 1023;
    h1s[si][k] = H1[(size_t)(s0+si)*BB*HH + (size_t)b*HH + k];
  }
  __syncthreads();
  {
    const int l = tid & 127, half = tid >> 7;
    const float4* er = (const float4*)(enc + ((size_t)l*BB + b)*HH + half*512);
    float a[8];
    #pragma unroll
    for (int s=0;s<8;s++) a[s]=0.f;
    for (int q=0;q<128;q++){
      float4 e = er[q];
      #pragma unroll
      for (int s=0;s<8;s++){
        const float4 h = *(const float4*)(&h1s[s][half*512 + q*4]);
        a[s] += h.x*e.x + h.y*e.y + h.z*e.z + h.w*e.w;
      }
    }
    #pragma unroll
    for (int s=0;s<8;s++) part[half][s][l] = a[s];
  }
  __syncthreads();
  for (int p = tid; p < 1024; p += 256){
    int s = p >> 7, l = p & 127;
    sc[s][l] = (part[0][s][l] + part[1][s][l]) * 0.03125f;
  }
  __syncthreads();
  {
    int s = tid >> 5, lid = tid & 31;
    float v0 = sc[s][lid], v1 = sc[s][lid+32], v2 = sc[s][lid+64], v3 = sc[s][lid+96];
    float m = fmaxf(fmaxf(v0,v1),fmaxf(v2,v3));
    for (int off=16; off>=1; off>>=1) m = fmaxf(m, __shfl_xor(m, off, 32));
    float e0=__expf(v0-m), e1=__expf(v1-m), e2=__expf(v2-m), e3=__expf(v3-m);
    float ssum = e0+e1+e2+e3;
    for (int off=16; off>=1; off>>=1) ssum += __shfl_xor(ssum, off, 32);
    float inv = 1.0f/ssum;
    sc[s][lid]=e0*inv; sc[s][lid+32]=e1*inv; sc[s][lid+64]=e2*inv; sc[s][lid+96]=e3*inv;
  }
  __syncthreads();
  {
    float acc[4][8];
    #pragma unroll
    for (int q=0;q<4;q++)
      #pragma unroll
      for (int s=0;s<8;s++) acc[q][s]=0.f;
    for (int l=0;l<128;l++){
      const float* er = enc + ((size_t)l*BB + b)*HH + tid;
      float a[8];
      #pragma unroll
      for (int s=0;s<8;s++) a[s] = sc[s][l];
      #pragma unroll
      for (int q=0;q<4;q++){
        float e = er[q*256];
        #pragma unroll
        for (int s=0;s<8;s++) acc[q][s] = fmaf(a[s], e, acc[q][s]);
      }
    }
    #pragma unroll
    for (int s=0;s<8;s++)
      #pragma unroll
      for (int q=0;q<4;q++)
        ctx[(size_t)(s0+s)*BB*HH + (size_t)b*HH + tid + q*256] = acc[q][s];
  }
}

__global__ __launch_bounds__(256) void k_logit(const float* __restrict__ H1, const float* __restrict__ ctx,
                        const float* __restrict__ Wout, const float* __restrict__ bout,
                        const int* __restrict__ inp, const int* __restrict__ ts,
                        float* __restrict__ outp, float* __restrict__ bce){
  __shared__ float rbuf[256];
  const int i = blockIdx.x;
  const int b = i >> 7, t = i & 127;
  const int v = inp[b*LL + t];
  const int tid = threadIdx.x;
  const float* h1r = H1 + ((size_t)t*BB + b)*HH;
  const float* cxr = ctx + ((size_t)t*BB + b)*HH;
  float acc = 0.f;
  #pragma unroll
  for (int q=0;q<4;q++){
    int k = tid + q*256;
    acc = fmaf(h1r[k], Wout[(size_t)k*VV + v], acc);
  }
  #pragma unroll
  for (int q=0;q<4;q++){
    int k = tid + q*256;
    acc = fmaf(cxr[k], Wout[(size_t)(k+1024)*VV + v], acc);
  }
  rbuf[tid] = acc;
  __syncthreads();
  for (int s=128; s>0; s>>=1){
    if (tid < s) rbuf[tid] += rbuf[tid+s];
    __syncthreads();
  }
  if (tid==0){
    float logit = rbuf[0] + bout[v];
    float p = 1.0f/(1.0f + expf(-logit));
    outp[b*LL + t] = p;
    float pc = fminf(fmaxf(p, 1e-12f), 1.0f - 1e-7f);
    float tg = (float)ts[0];
    bce[i] = -(tg*logf(pc) + (1.0f-tg)*log1pf(-pc));
  }
}

__global__ void k_loss(const float* __restrict__ bce, float* __restrict__ out0){
  __shared__ float rbuf[256];
  int tid = threadIdx.x;
  float s = 0.f;
  for (int i = tid; i < 2048; i += 256) s += bce[i];
  rbuf[tid] = s; __syncthreads();
  for (int st=128; st>0; st>>=1){
    if (tid<st) rbuf[tid]+=rbuf[tid+st];
    __syncthreads();
  }
  if (tid==0) out0[0] = rbuf[0] * (1.0f/(2048.0f*16.0f));
}

extern "C" void kernel_launch(void* const* d_in, const int* in_sizes, int n_in,
                              void* d_out, int out_size, void* d_ws, size_t ws_size,
                              hipStream_t stream){
  (void)in_sizes; (void)n_in; (void)out_size; (void)ws_size;
  const int*   inp   = (const int*)d_in[0];
  const int*   ts    = (const int*)d_in[2];
  const float* emb   = (const float*)d_in[3];
  const float* encW  = (const float*)d_in[4];
  const float* encb  = (const float*)d_in[5];
  const float* Wih0  = (const float*)d_in[6];
  const float* Whh0  = (const float*)d_in[7];
  const float* bih0  = (const float*)d_in[8];
  const float* bhh0  = (const float*)d_in[9];
  const float* Wih1  = (const float*)d_in[10];
  const float* Whh1  = (const float*)d_in[11];
  const float* bih1  = (const float*)d_in[12];
  const float* bhh1  = (const float*)d_in[13];
  const float* Wout  = (const float*)d_in[14];
  const float* bout  = (const float*)d_in[15];
  float* out = (float*)d_out;

  float* ws      = (float*)d_ws;
  float* enc_out = ws;
  float* H0      = enc_out + 2097152;
  float* H1      = H0 + 2097152;
  float* GX1     = H1 + 2097152;
  float* CTX     = GX1 + 6291456;
  float* gx0     = CTX + 2097152;
  float* bceb    = gx0 + 3072;
  int*   rowidx  = (int*)(bceb + 2048);
  int*   flags   = rowidx + 2048;          // 256 flags x 32 ints (128B lines)
  int*   go      = flags + 256*32;         // 1 go word on its own line

  hipMemsetAsync(flags, 0, (256*32 + 32)*sizeof(int), stream);
  k_rowidx<<<8,256,0,stream>>>(inp, rowidx);
  k_gemm<1,512><<<dim3(64,2),256,0,stream>>>(emb, rowidx, encW, encb, enc_out, HH);
  k_gx0<<<12,256,0,stream>>>(emb, Wih0, bih0, gx0);

  const float* enclast = enc_out + (size_t)127*BB*HH;

  k_chain_persist<<<NBLK,256,0,stream>>>(enclast, H0, Whh0, gx0, 0, 0, bhh0, flags, go, 0);
  k_gemm2<<<dim3(16,16),256,0,stream>>>(H0, Wih1, bih1, GX1);
  k_chain_persist<<<NBLK,256,0,stream>>>(enclast, H1, Whh1, GX1, BB*G3, G3, bhh1, flags, go, 1);
  k_attn<<<dim3(16,16),256,0,stream>>>(enc_out, H1, CTX);
  k_logit<<<2048,256,0,stream>>>(H1, CTX, Wout, bout, inp, ts, out+1, bceb);
  k_loss<<<1,256,0,stream>>>(bceb, out);
}